// Round 1
// baseline (320.078 us; speedup 1.0000x reference)
//
#include <hip/hip_runtime.h>

#define KSIZE 7
#define PAD 3
#define NEG_INF (-1e30f)
#define TILE_W 128
#define TILE_H 32
#define REG_W (TILE_W + KSIZE - 1)   // 134
#define REG_H (TILE_H + KSIZE - 1)   // 38
#define LDS_STRIDE 136               // pad to multiple of 4 floats for b128 alignment
#define IMG_H 512
#define IMG_W 512

__global__ __launch_bounds__(256)
void GrayscaleDilation2D_kernel(const float* __restrict__ img,
                                const float* __restrict__ filt,
                                float* __restrict__ out) {
    __shared__ float tile[REG_H * LDS_STRIDE];

    const int plane = blockIdx.z;
    const int x0 = blockIdx.x * TILE_W;
    const int y0 = blockIdx.y * TILE_H;
    const float* __restrict__ src = img + (size_t)plane * IMG_H * IMG_W;
    float* __restrict__ dst = out + (size_t)plane * IMG_H * IMG_W;

    const int tx = threadIdx.x;  // 0..31
    const int ty = threadIdx.y;  // 0..7
    const int t = ty * 32 + tx;

    // Filter: wave-uniform address + static indices -> scalar loads into SGPRs.
    float sf[KSIZE * KSIZE];
#pragma unroll
    for (int k = 0; k < KSIZE * KSIZE; ++k) sf[k] = filt[k];

    // Stage (REG_H x REG_W) input region into LDS with NEG_INF halo.
    for (int idx = t; idx < REG_H * REG_W; idx += 256) {
        const int r = idx / REG_W;
        const int c = idx - r * REG_W;
        const int gy = y0 - PAD + r;
        const int gx = x0 - PAD + c;
        float v = NEG_INF;
        if (gy >= 0 && gy < IMG_H && gx >= 0 && gx < IMG_W) v = src[gy * IMG_W + gx];
        tile[r * LDS_STRIDE + c] = v;
    }
    __syncthreads();

    // Each thread computes a 4x4 output tile:
    //   rows y0 + ty*4 + o (o=0..3), cols x0 + tx*4 + l (l=0..3)
    float acc[4][4];
#pragma unroll
    for (int o = 0; o < 4; ++o)
#pragma unroll
        for (int l = 0; l < 4; ++l) acc[o][l] = NEG_INF;

    const int row0 = ty * 4;
    const int col0 = tx * 4;

#pragma unroll
    for (int r = 0; r < 10; ++r) {
        const float* rp = &tile[(row0 + r) * LDS_STRIDE + col0];
        const float4 a  = *(const float4*)(rp);
        const float4 b  = *(const float4*)(rp + 4);
        const float4 c4 = *(const float4*)(rp + 8);
        const float v[12] = {a.x, a.y, a.z, a.w, b.x, b.y, b.z, b.w,
                             c4.x, c4.y, c4.z, c4.w};
        // output rows using input row r: o with 0 <= r-o <= 6
        const int omin = (r - 6 < 0) ? 0 : r - 6;
        const int omax = (r < 3) ? r : 3;
#pragma unroll
        for (int o = 0; o < 4; ++o) {
            if (o < omin || o > omax) continue;  // static after unroll
            const int i = r - o;  // filter row
#pragma unroll
            for (int j = 0; j < KSIZE; ++j) {
                const float f = sf[i * KSIZE + j];
                acc[o][0] = fmaxf(acc[o][0], v[j + 0] + f);
                acc[o][1] = fmaxf(acc[o][1], v[j + 1] + f);
                acc[o][2] = fmaxf(acc[o][2], v[j + 2] + f);
                acc[o][3] = fmaxf(acc[o][3], v[j + 3] + f);
            }
        }
    }

#pragma unroll
    for (int o = 0; o < 4; ++o) {
        float4 res = make_float4(acc[o][0], acc[o][1], acc[o][2], acc[o][3]);
        *(float4*)&dst[(size_t)(y0 + row0 + o) * IMG_W + (x0 + col0)] = res;
    }
}

extern "C" void kernel_launch(void* const* d_in, const int* in_sizes, int n_in,
                              void* d_out, int out_size, void* d_ws, size_t ws_size,
                              hipStream_t stream) {
    const float* img  = (const float*)d_in[0];
    const float* filt = (const float*)d_in[1];
    float* out = (float*)d_out;

    const int planes = in_sizes[0] / (IMG_H * IMG_W);  // B*C = 128
    dim3 grid(IMG_W / TILE_W, IMG_H / TILE_H, planes);
    dim3 block(32, 8);
    hipLaunchKernelGGL(GrayscaleDilation2D_kernel, grid, block, 0, stream,
                       img, filt, out);
}